// Round 12
// baseline (344.130 us; speedup 1.0000x reference)
//
#include <hip/hip_runtime.h>
#include <hip/hip_bf16.h>

typedef __hip_bfloat16 bf16;
typedef __bf16 bf16x8 __attribute__((ext_vector_type(8)));
typedef float f32x4 __attribute__((ext_vector_type(4)));
typedef unsigned short ushort_t;
typedef unsigned int uint_t;

#define NH 16
#define NB 2
#define SS 2048
#define EE 1024
#define DH 64
#define DV 128
#define PJW 6144           // fused projection output row width
#define Q1O 0
#define Q2O 1024
#define K1O 2048
#define K2O 3072
#define VO  4096
#define LAM0 0.7778701f    // 0.8 - 0.6*exp(-0.3*11)
#define LN_EPS 1e-5f
#define PSTR 72            // padded LDS row stride (bf16 elems)
#define SCLQ 0.18033688f   // 0.125 * log2(e): folded softmax scale + exp2 base

// ---- async global->LDS, 16B per lane (linear dest, lane-ordered) ----
__device__ __forceinline__ void gload_lds16(const bf16* g, bf16* l) {
    __builtin_amdgcn_global_load_lds(
        (const __attribute__((address_space(1))) void*)g,
        (__attribute__((address_space(3))) void*)l, 16, 0, 0);
}

__device__ __forceinline__ void stC(float* p, float v) { *p = v; }
__device__ __forceinline__ void stC(bf16* p, float v) { *p = __float2bfloat16(v); }

// ---------------- transpose-convert: W f32 [K][N] -> WT bf16 [noff+n][k] * scl ----------------
__global__ __launch_bounds__(256) void transp(const float* __restrict__ W,
                                              bf16* __restrict__ WT,
                                              int K, int N, int KST, int noff,
                                              float scl) {
    __shared__ float Ts[32][33];
    int n0 = blockIdx.x * 32, k0 = blockIdx.y * 32;
    int t = threadIdx.x, tx = t & 31, ty = t >> 5;
#pragma unroll
    for (int p = 0; p < 4; ++p)
        Ts[ty + 8 * p][tx] = W[(size_t)(k0 + ty + 8 * p) * N + n0 + tx];
    __syncthreads();
#pragma unroll
    for (int p = 0; p < 4; ++p)
        WT[(size_t)(noff + n0 + ty + 8 * p) * KST + k0 + tx] =
            __float2bfloat16(Ts[tx][ty + 8 * p] * scl);
}

// ---------------- MFMA GEMM (unchanged, verified R10) ----------------
template<int MODE, typename CT>
__global__ __launch_bounds__(256) void mgemm(const void* __restrict__ Ap,
                                             const bf16* __restrict__ Bt,
                                             CT* __restrict__ C,
                                             int M, int N, int K) {
    __shared__ bf16 Ahi[128][32];
    __shared__ bf16 Bs[128][32];

    const int t = threadIdx.x;
    const int w = t >> 6, l = t & 63;
    const int c = l & 15, g = l >> 4;
    const int wr = w >> 1, wc = w & 1;

    const int nwg = gridDim.x, cpx = nwg >> 3;
    const int sw = (blockIdx.x & 7) * cpx + (blockIdx.x >> 3);
    const int nbx = N >> 7;
    const int bx = sw % nbx, by = sw / nbx;
    const int row0 = by * 128, col0 = bx * 128;

    f32x4 acc[4][4];
    const f32x4 fz = {0.f, 0.f, 0.f, 0.f};
#pragma unroll
    for (int m = 0; m < 4; ++m)
#pragma unroll
        for (int n = 0; n < 4; ++n) acc[m][n] = fz;

    for (int k0 = 0; k0 < K; k0 += 32) {
        __syncthreads();
#pragma unroll
        for (int i = 0; i < 2; ++i) {
            int r = i * 64 + w * 16 + (l >> 2);
            gload_lds16(&Bt[(size_t)(col0 + r) * K + k0 + (l & 3) * 8],
                        &Bs[0][0] + (size_t)(i * 4 + w) * 512 + l * 8);
        }
        if constexpr (MODE == 1) {
            const float* A = (const float*)Ap;
#pragma unroll
            for (int i = 0; i < 4; ++i) {
                int r = (t >> 3) + 32 * i;
                const float4 v = *reinterpret_cast<const float4*>(
                    &A[(size_t)(row0 + r) * K + k0 + (t & 7) * 4]);
                float f[4] = {v.x, v.y, v.z, v.w};
                ushort_t hi[4];
#pragma unroll
                for (int j = 0; j < 4; ++j) {
                    bf16 h = __float2bfloat16(f[j]);
                    hi[j] = *reinterpret_cast<ushort_t*>(&h);
                }
                uint2 hp;
                hp.x = (unsigned)hi[0] | ((unsigned)hi[1] << 16);
                hp.y = (unsigned)hi[2] | ((unsigned)hi[3] << 16);
                *reinterpret_cast<uint2*>(&Ahi[r][(t & 7) * 4]) = hp;
            }
        } else {
            const bf16* A = (const bf16*)Ap;
#pragma unroll
            for (int i = 0; i < 2; ++i) {
                int r = i * 64 + w * 16 + (l >> 2);
                gload_lds16(&A[(size_t)(row0 + r) * K + k0 + (l & 3) * 8],
                            &Ahi[0][0] + (size_t)(i * 4 + w) * 512 + l * 8);
            }
        }
        __syncthreads();

        bf16x8 af[4], bfr[4];
#pragma unroll
        for (int m = 0; m < 4; ++m)
            af[m] = *reinterpret_cast<const bf16x8*>(&Ahi[wr * 64 + m * 16 + c][g * 8]);
#pragma unroll
        for (int n = 0; n < 4; ++n)
            bfr[n] = *reinterpret_cast<const bf16x8*>(&Bs[wc * 64 + n * 16 + c][g * 8]);
#pragma unroll
        for (int m = 0; m < 4; ++m)
#pragma unroll
            for (int n = 0; n < 4; ++n)
                acc[m][n] = __builtin_amdgcn_mfma_f32_16x16x32_bf16(af[m], bfr[n], acc[m][n], 0, 0, 0);
    }

#pragma unroll
    for (int m = 0; m < 4; ++m)
#pragma unroll
        for (int n = 0; n < 4; ++n)
#pragma unroll
            for (int r = 0; r < 4; ++r) {
                int row = row0 + wr * 64 + m * 16 + g * 4 + r;
                int col = col0 + wc * 64 + n * 16 + c;
                stC(&C[(size_t)row * N + col], acc[m][n][r]);
            }
}

// ---------------- MFMA differential flash attention + LayerNorm ----------------
// R12 = R11 + (1) P kept fully in registers: 8 bpermute moves/stream redistribute
// S^T fragments into PV A-operand layout (P LDS deleted -> 51KB -> 3 blocks/CU),
// (2) Vt XOR-swizzled at 8-key granularity (u8 ^= row>>3) killing the 4-way
// write conflicts that padding cannot fix (8-row stride ≡ 0 mod 32 banks).
__global__ __launch_bounds__(256) void attn_mfma(
        const bf16* __restrict__ cp,
        const float* __restrict__ lq1, const float* __restrict__ lk1,
        const float* __restrict__ lq2, const float* __restrict__ lk2,
        bf16* __restrict__ merged) {
    __shared__ ushort_t K1s[2][64][64];
    __shared__ ushort_t K2s[2][64][64];
    __shared__ ushort_t Vt[DV][PSTR];

    const int t = threadIdx.x;
    const int w = t >> 6, l = t & 63;
    const int g = l >> 4, c = l & 15;
    const int sb = g & 1, bg = g >> 1;

    const int bid = blockIdx.x;
    const int qt  = (SS / 64 - 1) - (bid >> 5);
    const int bh  = bid & 31;
    const int h   = bh & (NH - 1), b = bh >> 4;
    const int q0  = qt * 64;

    float lam;
    {
        float s1 = lq1[h * DH + l] * lk1[h * DH + l];
        float s2 = lq2[h * DH + l] * lk2[h * DH + l];
#pragma unroll
        for (int m = 32; m >= 1; m >>= 1) {
            s1 += __shfl_xor(s1, m, 64);
            s2 += __shfl_xor(s2, m, 64);
        }
        lam = __expf(s1) - __expf(s2) + LAM0;
    }

    bf16x8 qf1[2], qf2[2];
    {
        size_t qrow = (size_t)(b * SS + q0 + w * 16 + c) * PJW + h * DH;
#pragma unroll
        for (int ks = 0; ks < 2; ++ks) {
            qf1[ks] = *reinterpret_cast<const bf16x8*>(&cp[qrow + Q1O + 8 * g + 32 * ks]);
            qf2[ks] = *reinterpret_cast<const bf16x8*>(&cp[qrow + Q2O + 8 * g + 32 * ks]);
        }
    }

    // K tiles: LDS [64][64] with 16B-unit XOR swizzle on global source
    auto stageK = [&](int k0, int buf) {
#pragma unroll
        for (int i = 0; i < 2; ++i) {
            int u = i * 256 + t;              // 16B unit index in tile
            int row = u >> 3, j = u & 7;
            int jj = j ^ (row & 7);
            size_t gb = (size_t)(b * SS + k0 + row) * PJW + h * DH + jj * 8;
            gload_lds16(&cp[gb + K1O], (bf16*)&K1s[buf][0][0] + u * 8);
            gload_lds16(&cp[gb + K2O], (bf16*)&K2s[buf][0][0] + u * 8);
        }
    };
    uint4 va[4];
    const int vk4 = (t & 15) * 4, vc8 = (t >> 4) * 8;
    // Vt swizzled write column: u8' = (vk4>>3) ^ (row>>3); row>>3 == vc8>>3 for j<8
    const int vcol = (((vk4 >> 3) ^ ((vc8 >> 3) & 7)) & 7) * 8 + (vk4 & 4);
    auto loadV = [&](int k0) {
#pragma unroll
        for (int i = 0; i < 4; ++i)
            va[i] = *reinterpret_cast<const uint4*>(
                &cp[(size_t)(b * SS + k0 + vk4 + i) * PJW + VO + h * DV + vc8]);
    };

    f32x4 acc1[8], acc2[8];
    const f32x4 fz = {0.f, 0.f, 0.f, 0.f};
#pragma unroll
    for (int i = 0; i < 8; ++i) { acc1[i] = fz; acc2[i] = fz; }
    float m1 = -1e30f, m2 = -1e30f, l1 = 0.f, l2 = 0.f;   // l1/l2 per-lane partial

    // prologue: prefetch tile 0
    stageK(0, 0);
    loadV(0);

    for (int kt = 0; kt <= qt; ++kt) {
        const int k0 = kt * 64;
        const int cur = kt & 1;
        const bool diag = (kt == qt);

        // barrier A: drains vmcnt (K[cur] DMA + va landed); prev-tile LDS reads done.
        __syncthreads();

        if (kt < qt) stageK(k0 + 64, cur ^ 1);

        // Vt write from prefetched regs (transpose-pack, swizzled column)
#pragma unroll
        for (int j = 0; j < 8; ++j) {
            ushort_t e0 = reinterpret_cast<const ushort_t*>(&va[0])[j];
            ushort_t e1 = reinterpret_cast<const ushort_t*>(&va[1])[j];
            ushort_t e2 = reinterpret_cast<const ushort_t*>(&va[2])[j];
            ushort_t e3 = reinterpret_cast<const ushort_t*>(&va[3])[j];
            uint2 pk;
            pk.x = (unsigned)e0 | ((unsigned)e1 << 16);
            pk.y = (unsigned)e2 | ((unsigned)e3 << 16);
            *reinterpret_cast<uint2*>(&Vt[vc8 + j][vcol]) = pk;
        }
        if (kt < qt) loadV(k0 + 64);

        // barrier B: Vt visible; no vmcnt drain (prefetches stay in flight)
        asm volatile("s_waitcnt lgkmcnt(0)" ::: "memory");
        __builtin_amdgcn_sched_barrier(0);
        __builtin_amdgcn_s_barrier();
        __builtin_amdgcn_sched_barrier(0);

        // ---- QK^T from LDS (swizzled ds_read_b128); S in log2 domain ----
        f32x4 s1[4], s2[4];
        __builtin_amdgcn_s_setprio(1);
#pragma unroll
        for (int kb = 0; kb < 4; ++kb) {
            s1[kb] = fz; s2[kb] = fz;
            const int row = kb * 16 + c;
#pragma unroll
            for (int ks = 0; ks < 2; ++ks) {
                const int un = ((g + 4 * ks) ^ (row & 7)) * 8;
                bf16x8 kf1 = *reinterpret_cast<const bf16x8*>(&K1s[cur][row][un]);
                s1[kb] = __builtin_amdgcn_mfma_f32_16x16x32_bf16(kf1, qf1[ks], s1[kb], 0, 0, 0);
                bf16x8 kf2 = *reinterpret_cast<const bf16x8*>(&K2s[cur][row][un]);
                s2[kb] = __builtin_amdgcn_mfma_f32_16x16x32_bf16(kf2, qf2[ks], s2[kb], 0, 0, 0);
            }
        }
        __builtin_amdgcn_s_setprio(0);

        // ---- causal mask + dual online softmax (exp2 domain, defer-max) ----
        float mt1 = -1e30f, mt2 = -1e30f;
#pragma unroll
        for (int kb = 0; kb < 4; ++kb)
#pragma unroll
            for (int r = 0; r < 4; ++r) {
                float v1 = s1[kb][r];
                float v2 = s2[kb][r];
                if (diag && (kb * 16 + 4 * g + r) > (w * 16 + c)) { v1 = -1e30f; v2 = -1e30f; }
                s1[kb][r] = v1; s2[kb][r] = v2;
                mt1 = fmaxf(mt1, v1); mt2 = fmaxf(mt2, v2);
            }
        mt1 = fmaxf(mt1, __shfl_xor(mt1, 16, 64));
        mt1 = fmaxf(mt1, __shfl_xor(mt1, 32, 64));
        mt2 = fmaxf(mt2, __shfl_xor(mt2, 16, 64));
        mt2 = fmaxf(mt2, __shfl_xor(mt2, 32, 64));

        float f1 = 1.f, f2 = 1.f;
        if (!__all((mt1 - m1 <= 8.f) && (mt2 - m2 <= 8.f))) {
            float mn1 = fmaxf(m1, mt1), mn2 = fmaxf(m2, mt2);
            f1 = exp2f(m1 - mn1); f2 = exp2f(m2 - mn2);
            m1 = mn1; m2 = mn2;
#pragma unroll
            for (int r = 0; r < 4; ++r) {
                float f1o = __shfl(f1, 4 * g + r, 64);
                float f2o = __shfl(f2, 4 * g + r, 64);
#pragma unroll
                for (int vb = 0; vb < 8; ++vb) { acc1[vb][r] *= f1o; acc2[vb][r] *= f2o; }
            }
        }

        // exp2 + bf16-pack into pk[kb][e] (keys kb*16+4g+{2e,2e+1})
        float rs1 = 0.f, rs2 = 0.f;
        uint_t pk1[4][2], pk2[4][2];
#pragma unroll
        for (int kb = 0; kb < 4; ++kb) {
            ushort_t u1[4], u2[4];
#pragma unroll
            for (int r = 0; r < 4; ++r) {
                float p1 = exp2f(s1[kb][r] - m1); rs1 += p1;
                float p2 = exp2f(s2[kb][r] - m2); rs2 += p2;
                bf16 h1 = __float2bfloat16(p1);
                bf16 h2 = __float2bfloat16(p2);
                u1[r] = *reinterpret_cast<ushort_t*>(&h1);
                u2[r] = *reinterpret_cast<ushort_t*>(&h2);
            }
            pk1[kb][0] = (uint_t)u1[0] | ((uint_t)u1[1] << 16);
            pk1[kb][1] = (uint_t)u1[2] | ((uint_t)u1[3] << 16);
            pk2[kb][0] = (uint_t)u2[0] | ((uint_t)u2[1] << 16);
            pk2[kb][1] = (uint_t)u2[2] | ((uint_t)u2[3] << 16);
        }
        l1 = l1 * f1 + rs1;  l2 = l2 * f2 + rs2;

        // ---- in-register P redistribution: 8 shfl moves per stream ----
        // move(ks,e,ph): src lane sends pk[((srcLow)^ph)+2ks][e];
        // dest (g,c) reads lane (2(g&1) + ((g>>1)^ph))*16 + c.
        uint_t r1v[2][2][2], r2v[2][2][2];
#pragma unroll
        for (int ks = 0; ks < 2; ++ks)
#pragma unroll
            for (int e = 0; e < 2; ++e)
#pragma unroll
                for (int ph = 0; ph < 2; ++ph) {
                    uint_t sv1 = (sb ^ ph) ? pk1[1 + 2 * ks][e] : pk1[2 * ks][e];
                    uint_t sv2 = (sb ^ ph) ? pk2[1 + 2 * ks][e] : pk2[2 * ks][e];
                    int src = (2 * sb + (bg ^ ph)) * 16 + c;
                    r1v[ks][e][ph] = (uint_t)__shfl((int)sv1, src, 64);
                    r2v[ks][e][ph] = (uint_t)__shfl((int)sv2, src, 64);
                }

        // ---- PV: assemble A-frags from shfl results; Vt from swizzled LDS ----
        __builtin_amdgcn_s_setprio(1);
#pragma unroll
        for (int ks = 0; ks < 2; ++ks) {
            uint4 w1u, w2u;
            w1u.x = bg ? r1v[ks][0][1] : r1v[ks][0][0];
            w1u.y = bg ? r1v[ks][1][1] : r1v[ks][1][0];
            w1u.z = bg ? r1v[ks][0][0] : r1v[ks][0][1];
            w1u.w = bg ? r1v[ks][1][0] : r1v[ks][1][1];
            w2u.x = bg ? r2v[ks][0][1] : r2v[ks][0][0];
            w2u.y = bg ? r2v[ks][1][1] : r2v[ks][1][0];
            w2u.z = bg ? r2v[ks][0][0] : r2v[ks][0][1];
            w2u.w = bg ? r2v[ks][1][0] : r2v[ks][1][1];
            bf16x8 pa1 = *reinterpret_cast<bf16x8*>(&w1u);
            bf16x8 pa2 = *reinterpret_cast<bf16x8*>(&w2u);
#pragma unroll
            for (int vb = 0; vb < 8; ++vb) {
                const int u8p = ((g + 4 * ks) ^ (((c >> 3) + 2 * vb) & 7)) & 7;
                bf16x8 vf = *reinterpret_cast<const bf16x8*>(&Vt[c + 16 * vb][u8p * 8]);
                acc1[vb] = __builtin_amdgcn_mfma_f32_16x16x32_bf16(pa1, vf, acc1[vb], 0, 0, 0);
                acc2[vb] = __builtin_amdgcn_mfma_f32_16x16x32_bf16(pa2, vf, acc2[vb], 0, 0, 0);
            }
        }
        __builtin_amdgcn_s_setprio(0);
    }

    // ---- epilogue: finish l reduction, combine, LayerNorm(128), store ----
    l1 += __shfl_xor(l1, 16, 64); l1 += __shfl_xor(l1, 32, 64);
    l2 += __shfl_xor(l2, 16, 64); l2 += __shfl_xor(l2, 32, 64);
    float rl1[4], rl2[4];
#pragma unroll
    for (int r = 0; r < 4; ++r) {
        rl1[r] = __builtin_amdgcn_rcpf(__shfl(l1, 4 * g + r, 64));
        rl2[r] = __builtin_amdgcn_rcpf(__shfl(l2, 4 * g + r, 64));
    }
    float sum[4] = {0.f, 0.f, 0.f, 0.f};
#pragma unroll
    for (int vb = 0; vb < 8; ++vb)
#pragma unroll
        for (int r = 0; r < 4; ++r) {
            float v = acc1[vb][r] * rl1[r] - lam * (acc2[vb][r] * rl2[r]);
            acc1[vb][r] = v;
            sum[r] += v;
        }
#pragma unroll
    for (int r = 0; r < 4; ++r) {
#pragma unroll
        for (int m = 8; m >= 1; m >>= 1) sum[r] += __shfl_xor(sum[r], m, 64);
        sum[r] *= (1.f / 128.f);
    }
    float var[4] = {0.f, 0.f, 0.f, 0.f};
#pragma unroll
    for (int vb = 0; vb < 8; ++vb)
#pragma unroll
        for (int r = 0; r < 4; ++r) {
            float d = acc1[vb][r] - sum[r];
            var[r] += d * d;
        }
#pragma unroll
    for (int r = 0; r < 4; ++r) {
#pragma unroll
        for (int m = 8; m >= 1; m >>= 1) var[r] += __shfl_xor(var[r], m, 64);
        var[r] = rsqrtf(var[r] * (1.f / 128.f) + LN_EPS) * (1.f - LAM0);
    }
#pragma unroll
    for (int vb = 0; vb < 8; ++vb)
#pragma unroll
        for (int r = 0; r < 4; ++r) {
            size_t idx = (size_t)(b * SS + q0 + w * 16 + 4 * g + r) * (2 * EE)
                       + h * DV + c + 16 * vb;
            merged[idx] = __float2bfloat16((acc1[vb][r] - sum[r]) * var[r]);
        }
}

// ---------------- launch ----------------
extern "C" void kernel_launch(void* const* d_in, const int* in_sizes, int n_in,
                              void* d_out, int out_size, void* d_ws, size_t ws_size,
                              hipStream_t stream) {
    (void)in_sizes; (void)n_in; (void)out_size; (void)ws_size;
    const float* x   = (const float*)d_in[0];
    const float* Wq1 = (const float*)d_in[1];
    const float* Wq2 = (const float*)d_in[2];
    const float* Wk1 = (const float*)d_in[3];
    const float* Wk2 = (const float*)d_in[4];
    const float* Wv  = (const float*)d_in[5];
    const float* Wo  = (const float*)d_in[6];
    const float* lq1 = (const float*)d_in[7];
    const float* lk1 = (const float*)d_in[8];
    const float* lq2 = (const float*)d_in[9];
    const float* lk2 = (const float*)d_in[10];
    float* out = (float*)d_out;

    char* ws = (char*)d_ws;
    const size_t MB = 1ull << 20;
    bf16* wcT = (bf16*)(ws);
    bf16* cpj = (bf16*)(ws + 16 * MB);
    bf16* mg  = (bf16*)(ws);
    bf16* woT = (bf16*)(ws + 16 * MB);

    dim3 blk(256);
    transp<<<dim3(32, 32), blk, 0, stream>>>(Wq1, wcT, 1024, 1024, 1024, Q1O, SCLQ);
    transp<<<dim3(32, 32), blk, 0, stream>>>(Wq2, wcT, 1024, 1024, 1024, Q2O, SCLQ);
    transp<<<dim3(32, 32), blk, 0, stream>>>(Wk1, wcT, 1024, 1024, 1024, K1O, 1.0f);
    transp<<<dim3(32, 32), blk, 0, stream>>>(Wk2, wcT, 1024, 1024, 1024, K2O, 1.0f);
    transp<<<dim3(64, 32), blk, 0, stream>>>(Wv,  wcT, 1024, 2048, 1024, VO,  1.0f);
    mgemm<1, bf16><<<dim3((6144 / 128) * (4096 / 128)), blk, 0, stream>>>(
        x, wcT, cpj, 4096, 6144, 1024);
    attn_mfma<<<dim3(NB * NH * (SS / 64)), blk, 0, stream>>>(
        cpj, lq1, lk1, lq2, lk2, mg);
    transp<<<dim3(32, 64), blk, 0, stream>>>(Wo, woT, 2048, 1024, 2048, 0, 1.0f);
    mgemm<0, float><<<dim3((1024 / 128) * (4096 / 128)), blk, 0, stream>>>(
        mg, woT, out, 4096, 1024, 2048);
}

// Round 14
// 316.315 us; speedup vs baseline: 1.0879x; 1.0879x over previous
//
#include <hip/hip_runtime.h>
#include <hip/hip_bf16.h>

typedef __hip_bfloat16 bf16;
typedef __bf16 bf16x8 __attribute__((ext_vector_type(8)));
typedef float f32x4 __attribute__((ext_vector_type(4)));
typedef unsigned short ushort_t;

#define NH 16
#define NB 2
#define SS 2048
#define EE 1024
#define DH 64
#define DV 128
#define PJW 6144           // fused projection output row width
#define Q1O 0
#define Q2O 1024
#define K1O 2048
#define K2O 3072
#define VO  4096
#define LAM0 0.7778701f    // 0.8 - 0.6*exp(-0.3*11)
#define LN_EPS 1e-5f
#define PSTR 72            // padded LDS row stride (bf16 elems)
#define SCLQ 0.18033688f   // 0.125 * log2(e): folded softmax scale + exp2 base

// ---- async global->LDS, 16B per lane (linear dest, lane-ordered) ----
__device__ __forceinline__ void gload_lds16(const bf16* g, bf16* l) {
    __builtin_amdgcn_global_load_lds(
        (const __attribute__((address_space(1))) void*)g,
        (__attribute__((address_space(3))) void*)l, 16, 0, 0);
}

__device__ __forceinline__ void stC(float* p, float v) { *p = v; }
__device__ __forceinline__ void stC(bf16* p, float v) { *p = __float2bfloat16(v); }

// ---------------- fused transpose-convert for the 5 projection weights ----------------
// z<4: Wq1/Wq2/Wk1/Wk2 (N=1024, bx<32); z=4: Wv (N=2048, bx<64). All K=1024, KST=1024.
__global__ __launch_bounds__(256) void transp5(const float* __restrict__ W0,
                                               const float* __restrict__ W1,
                                               const float* __restrict__ W2,
                                               const float* __restrict__ W3,
                                               const float* __restrict__ W4,
                                               bf16* __restrict__ WT) {
    __shared__ float Ts[32][33];
    const int z = blockIdx.z;
    const int bx = blockIdx.x;
    if (z < 4 && bx >= 32) return;
    const float* W = (z == 0) ? W0 : (z == 1) ? W1 : (z == 2) ? W2 : (z == 3) ? W3 : W4;
    const int N = (z == 4) ? 2048 : 1024;
    const int noff = z * 1024;
    const float scl = (z < 2) ? SCLQ : 1.0f;
    int n0 = bx * 32, k0 = blockIdx.y * 32;
    int t = threadIdx.x, tx = t & 31, ty = t >> 5;
#pragma unroll
    for (int p = 0; p < 4; ++p)
        Ts[ty + 8 * p][tx] = W[(size_t)(k0 + ty + 8 * p) * N + n0 + tx];
    __syncthreads();
#pragma unroll
    for (int p = 0; p < 4; ++p)
        WT[(size_t)(noff + n0 + ty + 8 * p) * 1024 + k0 + tx] =
            __float2bfloat16(Ts[tx][ty + 8 * p] * scl);
}

// ---------------- transpose-convert (Wo): W f32 [K][N] -> WT bf16 [n][k] ----------------
__global__ __launch_bounds__(256) void transp(const float* __restrict__ W,
                                              bf16* __restrict__ WT,
                                              int K, int N, int KST, int noff,
                                              float scl) {
    __shared__ float Ts[32][33];
    int n0 = blockIdx.x * 32, k0 = blockIdx.y * 32;
    int t = threadIdx.x, tx = t & 31, ty = t >> 5;
#pragma unroll
    for (int p = 0; p < 4; ++p)
        Ts[ty + 8 * p][tx] = W[(size_t)(k0 + ty + 8 * p) * N + n0 + tx];
    __syncthreads();
#pragma unroll
    for (int p = 0; p < 4; ++p)
        WT[(size_t)(noff + n0 + ty + 8 * p) * KST + k0 + tx] =
            __float2bfloat16(Ts[tx][ty + 8 * p] * scl);
}

// ---------------- MFMA GEMM (unchanged, verified R10) ----------------
template<int MODE, typename CT>
__global__ __launch_bounds__(256) void mgemm(const void* __restrict__ Ap,
                                             const bf16* __restrict__ Bt,
                                             CT* __restrict__ C,
                                             int M, int N, int K) {
    __shared__ bf16 Ahi[128][32];
    __shared__ bf16 Bs[128][32];

    const int t = threadIdx.x;
    const int w = t >> 6, l = t & 63;
    const int c = l & 15, g = l >> 4;
    const int wr = w >> 1, wc = w & 1;

    const int nwg = gridDim.x, cpx = nwg >> 3;
    const int sw = (blockIdx.x & 7) * cpx + (blockIdx.x >> 3);
    const int nbx = N >> 7;
    const int bx = sw % nbx, by = sw / nbx;
    const int row0 = by * 128, col0 = bx * 128;

    f32x4 acc[4][4];
    const f32x4 fz = {0.f, 0.f, 0.f, 0.f};
#pragma unroll
    for (int m = 0; m < 4; ++m)
#pragma unroll
        for (int n = 0; n < 4; ++n) acc[m][n] = fz;

    for (int k0 = 0; k0 < K; k0 += 32) {
        __syncthreads();
#pragma unroll
        for (int i = 0; i < 2; ++i) {
            int r = i * 64 + w * 16 + (l >> 2);
            gload_lds16(&Bt[(size_t)(col0 + r) * K + k0 + (l & 3) * 8],
                        &Bs[0][0] + (size_t)(i * 4 + w) * 512 + l * 8);
        }
        if constexpr (MODE == 1) {
            const float* A = (const float*)Ap;
#pragma unroll
            for (int i = 0; i < 4; ++i) {
                int r = (t >> 3) + 32 * i;
                const float4 v = *reinterpret_cast<const float4*>(
                    &A[(size_t)(row0 + r) * K + k0 + (t & 7) * 4]);
                float f[4] = {v.x, v.y, v.z, v.w};
                ushort_t hi[4];
#pragma unroll
                for (int j = 0; j < 4; ++j) {
                    bf16 h = __float2bfloat16(f[j]);
                    hi[j] = *reinterpret_cast<ushort_t*>(&h);
                }
                uint2 hp;
                hp.x = (unsigned)hi[0] | ((unsigned)hi[1] << 16);
                hp.y = (unsigned)hi[2] | ((unsigned)hi[3] << 16);
                *reinterpret_cast<uint2*>(&Ahi[r][(t & 7) * 4]) = hp;
            }
        } else {
            const bf16* A = (const bf16*)Ap;
#pragma unroll
            for (int i = 0; i < 2; ++i) {
                int r = i * 64 + w * 16 + (l >> 2);
                gload_lds16(&A[(size_t)(row0 + r) * K + k0 + (l & 3) * 8],
                            &Ahi[0][0] + (size_t)(i * 4 + w) * 512 + l * 8);
            }
        }
        __syncthreads();

        bf16x8 af[4], bfr[4];
#pragma unroll
        for (int m = 0; m < 4; ++m)
            af[m] = *reinterpret_cast<const bf16x8*>(&Ahi[wr * 64 + m * 16 + c][g * 8]);
#pragma unroll
        for (int n = 0; n < 4; ++n)
            bfr[n] = *reinterpret_cast<const bf16x8*>(&Bs[wc * 64 + n * 16 + c][g * 8]);
#pragma unroll
        for (int m = 0; m < 4; ++m)
#pragma unroll
            for (int n = 0; n < 4; ++n)
                acc[m][n] = __builtin_amdgcn_mfma_f32_16x16x32_bf16(af[m], bfr[n], acc[m][n], 0, 0, 0);
    }

#pragma unroll
    for (int m = 0; m < 4; ++m)
#pragma unroll
        for (int n = 0; n < 4; ++n)
#pragma unroll
            for (int r = 0; r < 4; ++r) {
                int row = row0 + wr * 64 + m * 16 + g * 4 + r;
                int col = col0 + wc * 64 + n * 16 + c;
                stC(&C[(size_t)row * N + col], acc[m][n][r]);
            }
}

// ---------------- MFMA differential flash attention + LayerNorm ----------------
// R14 = R10 proven structure (tracked/defer-max softmax, late barrier B, K dbuf
// via global_load_lds + V reg-prefetch) + R13's hoisted pointer addressing +
// R11's deferred per-lane l accumulation. exp2-domain (SCLQ folded into Wq).
__global__ __launch_bounds__(256) void attn_mfma(
        const bf16* __restrict__ cp,
        const float* __restrict__ lq1, const float* __restrict__ lk1,
        const float* __restrict__ lq2, const float* __restrict__ lk2,
        bf16* __restrict__ merged) {
    __shared__ ushort_t K1s[2][64][64];
    __shared__ ushort_t K2s[2][64][64];
    __shared__ ushort_t Vt[DV][PSTR];
    __shared__ ushort_t P1s[4][16][PSTR];
    __shared__ ushort_t P2s[4][16][PSTR];

    const int t = threadIdx.x;
    const int w = t >> 6, l = t & 63;
    const int g = l >> 4, c = l & 15;

    const int bid = blockIdx.x;
    const int qt  = (SS / 64 - 1) - (bid >> 5);
    const int bh  = bid & 31;
    const int h   = bh & (NH - 1), b = bh >> 4;
    const int q0  = qt * 64;

    float lam;
    {
        float s1 = lq1[h * DH + l] * lk1[h * DH + l];
        float s2 = lq2[h * DH + l] * lk2[h * DH + l];
#pragma unroll
        for (int m = 32; m >= 1; m >>= 1) {
            s1 += __shfl_xor(s1, m, 64);
            s2 += __shfl_xor(s2, m, 64);
        }
        lam = __expf(s1) - __expf(s2) + LAM0;
    }

    bf16x8 qf1[2], qf2[2];
    {
        size_t qrow = (size_t)(b * SS + q0 + w * 16 + c) * PJW + h * DH;
#pragma unroll
        for (int ks = 0; ks < 2; ++ks) {
            qf1[ks] = *reinterpret_cast<const bf16x8*>(&cp[qrow + Q1O + 8 * g + 32 * ks]);
            qf2[ks] = *reinterpret_cast<const bf16x8*>(&cp[qrow + Q2O + 8 * g + 32 * ks]);
        }
    }

    // ---- hoisted staging addresses (advance by TSTEP per tile; proven R13) ----
    const size_t TSTEP = (size_t)64 * PJW;
    const int u0 = t, u1 = 256 + t;
    const int r0u = u0 >> 3, jj0 = (u0 & 7) ^ (r0u & 7);
    const int r1u = u1 >> 3, jj1 = (u1 & 7) ^ (r1u & 7);
    const bf16* k1p0 = cp + (size_t)(b * SS + r0u) * PJW + h * DH + jj0 * 8 + K1O;
    const bf16* k1p1 = cp + (size_t)(b * SS + r1u) * PJW + h * DH + jj1 * 8 + K1O;
    const bf16* k2p0 = k1p0 + (K2O - K1O);
    const bf16* k2p1 = k1p1 + (K2O - K1O);
    auto stageK = [&](int buf) {
        bf16* d1 = (bf16*)&K1s[buf][0][0];
        bf16* d2 = (bf16*)&K2s[buf][0][0];
        gload_lds16(k1p0, d1 + u0 * 8);
        gload_lds16(k1p1, d1 + u1 * 8);
        gload_lds16(k2p0, d2 + u0 * 8);
        gload_lds16(k2p1, d2 + u1 * 8);
        k1p0 += TSTEP; k1p1 += TSTEP; k2p0 += TSTEP; k2p1 += TSTEP;
    };
    uint4 va[4];
    const int vk4 = (t & 15) * 4, vc8 = (t >> 4) * 8;
    const bf16* vp0 = cp + (size_t)(b * SS + vk4 + 0) * PJW + VO + h * DV + vc8;
    const bf16* vp1 = cp + (size_t)(b * SS + vk4 + 1) * PJW + VO + h * DV + vc8;
    const bf16* vp2 = cp + (size_t)(b * SS + vk4 + 2) * PJW + VO + h * DV + vc8;
    const bf16* vp3 = cp + (size_t)(b * SS + vk4 + 3) * PJW + VO + h * DV + vc8;
    auto loadV = [&]() {
        va[0] = *reinterpret_cast<const uint4*>(vp0);
        va[1] = *reinterpret_cast<const uint4*>(vp1);
        va[2] = *reinterpret_cast<const uint4*>(vp2);
        va[3] = *reinterpret_cast<const uint4*>(vp3);
        vp0 += TSTEP; vp1 += TSTEP; vp2 += TSTEP; vp3 += TSTEP;
    };

    f32x4 acc1[8], acc2[8];
    const f32x4 fz = {0.f, 0.f, 0.f, 0.f};
#pragma unroll
    for (int i = 0; i < 8; ++i) { acc1[i] = fz; acc2[i] = fz; }
    float m1 = -1e30f, m2 = -1e30f, l1 = 0.f, l2 = 0.f;   // l per-lane partial

    // prologue: prefetch tile 0
    stageK(0);
    loadV();

    for (int kt = 0; kt <= qt; ++kt) {
        const int cur = kt & 1;
        const bool diag = (kt == qt);

        // barrier A: drains vmcnt (K[cur] DMA + va landed); prev-tile LDS reads done.
        __syncthreads();

        // issue next tile's K DMA first (max overlap window)
        if (kt < qt) stageK(cur ^ 1);

        // Vt write from prefetched regs (transpose-pack)
#pragma unroll
        for (int j = 0; j < 8; ++j) {
            ushort_t e0 = reinterpret_cast<const ushort_t*>(&va[0])[j];
            ushort_t e1 = reinterpret_cast<const ushort_t*>(&va[1])[j];
            ushort_t e2 = reinterpret_cast<const ushort_t*>(&va[2])[j];
            ushort_t e3 = reinterpret_cast<const ushort_t*>(&va[3])[j];
            uint2 pk;
            pk.x = (unsigned)e0 | ((unsigned)e1 << 16);
            pk.y = (unsigned)e2 | ((unsigned)e3 << 16);
            *reinterpret_cast<uint2*>(&Vt[vc8 + j][vk4]) = pk;
        }
        if (kt < qt) loadV();

        // ---- QK^T from LDS (swizzled ds_read_b128); S in log2 domain ----
        f32x4 s1[4], s2[4];
        __builtin_amdgcn_s_setprio(1);
#pragma unroll
        for (int kb = 0; kb < 4; ++kb) {
            s1[kb] = fz; s2[kb] = fz;
            const int row = kb * 16 + c;
#pragma unroll
            for (int ks = 0; ks < 2; ++ks) {
                const int un = ((g + 4 * ks) ^ (row & 7)) * 8;
                bf16x8 kf1 = *reinterpret_cast<const bf16x8*>(&K1s[cur][row][un]);
                s1[kb] = __builtin_amdgcn_mfma_f32_16x16x32_bf16(kf1, qf1[ks], s1[kb], 0, 0, 0);
                bf16x8 kf2 = *reinterpret_cast<const bf16x8*>(&K2s[cur][row][un]);
                s2[kb] = __builtin_amdgcn_mfma_f32_16x16x32_bf16(kf2, qf2[ks], s2[kb], 0, 0, 0);
            }
        }
        __builtin_amdgcn_s_setprio(0);

        // ---- causal mask + dual online softmax (exp2 domain, defer-max) ----
        float mt1 = -1e30f, mt2 = -1e30f;
#pragma unroll
        for (int kb = 0; kb < 4; ++kb)
#pragma unroll
            for (int r = 0; r < 4; ++r) {
                float v1 = s1[kb][r];
                float v2 = s2[kb][r];
                if (diag && (kb * 16 + 4 * g + r) > (w * 16 + c)) { v1 = -1e30f; v2 = -1e30f; }
                s1[kb][r] = v1; s2[kb][r] = v2;
                mt1 = fmaxf(mt1, v1); mt2 = fmaxf(mt2, v2);
            }
        mt1 = fmaxf(mt1, __shfl_xor(mt1, 16, 64));
        mt1 = fmaxf(mt1, __shfl_xor(mt1, 32, 64));
        mt2 = fmaxf(mt2, __shfl_xor(mt2, 16, 64));
        mt2 = fmaxf(mt2, __shfl_xor(mt2, 32, 64));

        float f1 = 1.f, f2 = 1.f;
        if (!__all((mt1 - m1 <= 8.f) && (mt2 - m2 <= 8.f))) {
            float mn1 = fmaxf(m1, mt1), mn2 = fmaxf(m2, mt2);
            f1 = exp2f(m1 - mn1); f2 = exp2f(m2 - mn2);
            m1 = mn1; m2 = mn2;
#pragma unroll
            for (int r = 0; r < 4; ++r) {
                float f1o = __shfl(f1, 4 * g + r, 64);
                float f2o = __shfl(f2, 4 * g + r, 64);
#pragma unroll
                for (int vb = 0; vb < 8; ++vb) { acc1[vb][r] *= f1o; acc2[vb][r] *= f2o; }
            }
        }

        // per-lane partial row sums (cross-lane reduce deferred; f is q-uniform)
        float rs1 = 0.f, rs2 = 0.f;
#pragma unroll
        for (int kb = 0; kb < 4; ++kb) {
            ushort_t u1v[4], u2v[4];
#pragma unroll
            for (int r = 0; r < 4; ++r) {
                float p1 = exp2f(s1[kb][r] - m1); rs1 += p1;
                float p2 = exp2f(s2[kb][r] - m2); rs2 += p2;
                bf16 h1 = __float2bfloat16(p1);
                bf16 h2 = __float2bfloat16(p2);
                u1v[r] = *reinterpret_cast<ushort_t*>(&h1);
                u2v[r] = *reinterpret_cast<ushort_t*>(&h2);
            }
            uint2 w1, w2;
            w1.x = (unsigned)u1v[0] | ((unsigned)u1v[1] << 16);
            w1.y = (unsigned)u1v[2] | ((unsigned)u1v[3] << 16);
            w2.x = (unsigned)u2v[0] | ((unsigned)u2v[1] << 16);
            w2.y = (unsigned)u2v[2] | ((unsigned)u2v[3] << 16);
            *reinterpret_cast<uint2*>(&P1s[w][c][kb * 16 + 4 * g]) = w1;
            *reinterpret_cast<uint2*>(&P2s[w][c][kb * 16 + 4 * g]) = w2;
        }
        l1 = l1 * f1 + rs1;  l2 = l2 * f2 + rs2;

        // barrier B: Vt + P visible; NO vmcnt drain (prefetches stay in flight)
        asm volatile("s_waitcnt lgkmcnt(0)" ::: "memory");
        __builtin_amdgcn_sched_barrier(0);
        __builtin_amdgcn_s_barrier();
        __builtin_amdgcn_sched_barrier(0);

        // ---- PV ----
        __builtin_amdgcn_s_setprio(1);
#pragma unroll
        for (int ks = 0; ks < 2; ++ks) {
            bf16x8 pa1 = *reinterpret_cast<const bf16x8*>(&P1s[w][c][8 * g + 32 * ks]);
            bf16x8 pa2 = *reinterpret_cast<const bf16x8*>(&P2s[w][c][8 * g + 32 * ks]);
#pragma unroll
            for (int vb = 0; vb < 8; ++vb) {
                bf16x8 vf = *reinterpret_cast<const bf16x8*>(&Vt[c + 16 * vb][8 * g + 32 * ks]);
                acc1[vb] = __builtin_amdgcn_mfma_f32_16x16x32_bf16(pa1, vf, acc1[vb], 0, 0, 0);
                acc2[vb] = __builtin_amdgcn_mfma_f32_16x16x32_bf16(pa2, vf, acc2[vb], 0, 0, 0);
            }
        }
        __builtin_amdgcn_s_setprio(0);
    }

    // ---- epilogue: finish l reduction, combine, LayerNorm(128), store ----
    l1 += __shfl_xor(l1, 16, 64); l1 += __shfl_xor(l1, 32, 64);
    l2 += __shfl_xor(l2, 16, 64); l2 += __shfl_xor(l2, 32, 64);
    float rl1[4], rl2[4];
#pragma unroll
    for (int r = 0; r < 4; ++r) {
        rl1[r] = __builtin_amdgcn_rcpf(__shfl(l1, 4 * g + r, 64));
        rl2[r] = __builtin_amdgcn_rcpf(__shfl(l2, 4 * g + r, 64));
    }
    float sum[4] = {0.f, 0.f, 0.f, 0.f};
#pragma unroll
    for (int vb = 0; vb < 8; ++vb)
#pragma unroll
        for (int r = 0; r < 4; ++r) {
            float v = acc1[vb][r] * rl1[r] - lam * (acc2[vb][r] * rl2[r]);
            acc1[vb][r] = v;
            sum[r] += v;
        }
#pragma unroll
    for (int r = 0; r < 4; ++r) {
#pragma unroll
        for (int m = 8; m >= 1; m >>= 1) sum[r] += __shfl_xor(sum[r], m, 64);
        sum[r] *= (1.f / 128.f);
    }
    float var[4] = {0.f, 0.f, 0.f, 0.f};
#pragma unroll
    for (int vb = 0; vb < 8; ++vb)
#pragma unroll
        for (int r = 0; r < 4; ++r) {
            float d = acc1[vb][r] - sum[r];
            var[r] += d * d;
        }
#pragma unroll
    for (int r = 0; r < 4; ++r) {
#pragma unroll
        for (int m = 8; m >= 1; m >>= 1) var[r] += __shfl_xor(var[r], m, 64);
        var[r] = rsqrtf(var[r] * (1.f / 128.f) + LN_EPS) * (1.f - LAM0);
    }
#pragma unroll
    for (int vb = 0; vb < 8; ++vb)
#pragma unroll
        for (int r = 0; r < 4; ++r) {
            size_t idx = (size_t)(b * SS + q0 + w * 16 + 4 * g + r) * (2 * EE)
                       + h * DV + c + 16 * vb;
            merged[idx] = __float2bfloat16((acc1[vb][r] - sum[r]) * var[r]);
        }
}

// ---------------- launch ----------------
extern "C" void kernel_launch(void* const* d_in, const int* in_sizes, int n_in,
                              void* d_out, int out_size, void* d_ws, size_t ws_size,
                              hipStream_t stream) {
    (void)in_sizes; (void)n_in; (void)out_size; (void)ws_size;
    const float* x   = (const float*)d_in[0];
    const float* Wq1 = (const float*)d_in[1];
    const float* Wq2 = (const float*)d_in[2];
    const float* Wk1 = (const float*)d_in[3];
    const float* Wk2 = (const float*)d_in[4];
    const float* Wv  = (const float*)d_in[5];
    const float* Wo  = (const float*)d_in[6];
    const float* lq1 = (const float*)d_in[7];
    const float* lk1 = (const float*)d_in[8];
    const float* lq2 = (const float*)d_in[9];
    const float* lk2 = (const float*)d_in[10];
    float* out = (float*)d_out;

    char* ws = (char*)d_ws;
    const size_t MB = 1ull << 20;
    bf16* wcT = (bf16*)(ws);
    bf16* cpj = (bf16*)(ws + 16 * MB);
    bf16* mg  = (bf16*)(ws);
    bf16* woT = (bf16*)(ws + 16 * MB);

    dim3 blk(256);
    // fused transpose of all 5 projection weights (Wq pre-scaled by SCLQ)
    transp5<<<dim3(64, 32, 5), blk, 0, stream>>>(Wq1, Wq2, Wk1, Wk2, Wv, wcT);
    mgemm<1, bf16><<<dim3((6144 / 128) * (4096 / 128)), blk, 0, stream>>>(
        x, wcT, cpj, 4096, 6144, 1024);
    attn_mfma<<<dim3(NB * NH * (SS / 64)), blk, 0, stream>>>(
        cpj, lq1, lk1, lq2, lk2, mg);
    transp<<<dim3(32, 64), blk, 0, stream>>>(Wo, woT, 2048, 1024, 2048, 0, 1.0f);
    mgemm<0, float><<<dim3((1024 / 128) * (4096 / 128)), blk, 0, stream>>>(
        mg, woT, out, 4096, 1024, 2048);
}